// Round 13
// baseline (89.931 us; speedup 1.0000x reference)
//
#include <hip/hip_runtime.h>

#define NT 2000000
#define NE 20000
#define NT4 (NT / 4)          // 500000, exact
#define K1_BLOCKS 1024
#define K1_WAVES (K1_BLOCKS * 4)   // 4096 -> 4.88 events/wave (balanced)
#define K2_BLOCKS (NE / 16)   // 1250, exact

using bf16x8 = __attribute__((ext_vector_type(8))) __bf16;
using half8  = __attribute__((ext_vector_type(8))) _Float16;
using half2v = __attribute__((ext_vector_type(2))) _Float16;
using f32x4  = __attribute__((ext_vector_type(4))) float;
using f32x2  = __attribute__((ext_vector_type(2))) float;
using fvec4  = __attribute__((ext_vector_type(4))) float;

// hi/lo bf16 split of 8 consecutive f32 (k2 precision)
__device__ __forceinline__ void load_bsplit(const float* __restrict__ p,
                                            bf16x8& hi, bf16x8& lo) {
    fvec4 a = *(const fvec4*)p;
    fvec4 b = *(const fvec4*)(p + 4);
#pragma unroll
    for (int e = 0; e < 4; e++) {
        float v  = a[e];
        __bf16 h = (__bf16)v;
        hi[e]    = h;
        lo[e]    = (__bf16)(v - (float)h);
        float v2  = b[e];
        __bf16 h2 = (__bf16)v2;
        hi[e + 4] = h2;
        lo[e + 4] = (__bf16)(v2 - (float)h2);
    }
}

// 8 consecutive f32 -> f16x8
__device__ __forceinline__ half8 load_h8(const float* __restrict__ p) {
    fvec4 a = *(const fvec4*)p;
    fvec4 b = *(const fvec4*)(p + 4);
    half8 r;
#pragma unroll
    for (int e = 0; e < 4; e++) {
        r[e]     = (_Float16)a[e];
        r[e + 4] = (_Float16)b[e];
    }
    return r;
}

// ---------------- K0: event offsets via boundary scatter + zero s2 ----------------
__global__ __launch_bounds__(256) void k0_offsets(
    const int* __restrict__ seg, int* __restrict__ off, float* __restrict__ s2) {
    if (blockIdx.x == 0 && threadIdx.x < 64) s2[threadIdx.x] = 0.f;
    const int g = blockIdx.x * 256 + threadIdx.x;
    if (g >= NT4) return;
    const int idx4 = g * 4;
    const int4 s = *(const int4*)(seg + idx4);
    int prev = (g == 0) ? -1 : seg[idx4 - 1];
    int vals[4] = {s.x, s.y, s.z, s.w};
#pragma unroll
    for (int k = 0; k < 4; k++) {
        const int cur = vals[k];
        if (cur != prev) {
            for (int e = prev + 1; e <= cur; ++e) off[e] = idx4 + k;
        }
        prev = cur;
    }
    if (idx4 + 3 == NT - 1) {
        for (int e = prev + 1; e <= NE; ++e) off[e] = NT;
    }
}

// ---------------- K1: fused phi1 (2 layers) + per-event sum, WAVE PER EVENT ------
// r12 lesson: occupancy is pinned at ~2.5 waves/SIMD by invisible AGPR
// allocation (~200 unified regs/wave) -- grid size doesn't change it. So this
// round adds ILP inside the wave: TWO independent full-block chains per
// iteration (sjA/sjB), tail hoisted out of the hot loop (no per-lane bounds
// checks on full blocks). Tripwire: FETCH_SIZE ~4.6MB (scratch spill -> revert).
__global__ __launch_bounds__(256, 4) void k1_phi1(
    const float* __restrict__ values, const int* __restrict__ off,
    const float* __restrict__ w0, const float* __restrict__ b0,
    const float* __restrict__ w1, const float* __restrict__ b1,
    float* __restrict__ ev) {
    const int tid = threadIdx.x;
    const int w   = tid >> 6;
    const int l   = tid & 63;
    const int l15 = l & 15;
    const int l4  = l >> 4;

    // B fragments for W1 (f16): lane holds col j=16jf+l15, k = 32kf+8*l4+e
    half8 Bh[2][4];
#pragma unroll
    for (int kf = 0; kf < 2; kf++)
#pragma unroll
        for (int jf = 0; jf < 4; jf++)
            Bh[kf][jf] = load_h8(w1 + (jf * 16 + l15) * 64 + kf * 32 + l4 * 8);

    // layer-1 weights as f16 pairs -> v_pk_fma_f16 in the A-build
    half2v w0h[2][4], b0h[2][4];
#pragma unroll
    for (int kf = 0; kf < 2; kf++) {
        const int kb = kf * 32 + l4 * 8;
#pragma unroll
        for (int e2 = 0; e2 < 4; e2++) {
            f32x2 wp = *(const f32x2*)(w0 + kb + 2 * e2);
            f32x2 bp = *(const f32x2*)(b0 + kb + 2 * e2);
            w0h[kf][e2] = half2v{(_Float16)wp[0], (_Float16)wp[1]};
            b0h[kf][e2] = half2v{(_Float16)bp[0], (_Float16)bp[1]};
        }
    }
    // bias as ready-made C fragment
    f32x4 biasC[4];
#pragma unroll
    for (int jf = 0; jf < 4; jf++) {
        const float bj = b1[jf * 16 + l15];
#pragma unroll
        for (int r = 0; r < 4; r++) biasC[jf][r] = bj;
    }

    // h1 = relu(v*w0+b0) in packed f16, directly in A-fragment layout
    auto buildA = [&](_Float16 v, half8& A0, half8& A1) {
        const half2v vv = {v, v};
#pragma unroll
        for (int e2 = 0; e2 < 4; e2++) {
            half2v h0 = vv * w0h[0][e2] + b0h[0][e2];   // v_pk_fma_f16
            half2v h1 = vv * w0h[1][e2] + b0h[1][e2];
            const _Float16 z = (_Float16)0.f;
            A0[2 * e2]     = h0[0] > z ? h0[0] : z;
            A0[2 * e2 + 1] = h0[1] > z ? h0[1] : z;
            A1[2 * e2]     = h1[0] > z ? h1[0] : z;
            A1[2 * e2 + 1] = h1[1] > z ? h1[1] : z;
        }
    };
    // 2-MFMA chain per jf, relu'd and folded into running partials
    auto chain = [&](const half8& A0, const half8& A1, float* sj) {
#pragma unroll
        for (int jf = 0; jf < 4; jf++) {
            f32x4 tt = __builtin_amdgcn_mfma_f32_16x16x32_f16(
                A0, Bh[0][jf], biasC[jf], 0, 0, 0);
            tt = __builtin_amdgcn_mfma_f32_16x16x32_f16(
                A1, Bh[1][jf], tt, 0, 0, 0);
            sj[jf] += (fmaxf(tt[0], 0.f) + fmaxf(tt[1], 0.f)) +
                      (fmaxf(tt[2], 0.f) + fmaxf(tt[3], 0.f));
        }
    };
    auto chainTail = [&](const half8& A0, const half8& A1, float* sj, int rem) {
#pragma unroll
        for (int jf = 0; jf < 4; jf++) {
            f32x4 tt = __builtin_amdgcn_mfma_f32_16x16x32_f16(
                A0, Bh[0][jf], biasC[jf], 0, 0, 0);
            tt = __builtin_amdgcn_mfma_f32_16x16x32_f16(
                A1, Bh[1][jf], tt, 0, 0, 0);
            float s = 0.f;
#pragma unroll
            for (int r = 0; r < 4; r++) {
                const bool ok = (l4 * 4 + r) < rem;
                s += ok ? fmaxf(tt[r], 0.f) : 0.f;
            }
            sj[jf] += s;
        }
    };

    // 2-step butterfly: lane l ends holding full column sum of feature j==l
    const bool bit0 = (l & 16) != 0;
    const bool bit1 = (l & 32) != 0;
    auto reduce4 = [&](const float sj[4]) -> float {
        float send01 = bit0 ? sj[0] : sj[1];
        float keep01 = bit0 ? sj[1] : sj[0];
        float c01 = keep01 + __shfl_xor(send01, 16);
        float send23 = bit0 ? sj[2] : sj[3];
        float keep23 = bit0 ? sj[3] : sj[2];
        float c23 = keep23 + __shfl_xor(send23, 16);
        float send = bit1 ? c01 : c23;
        float keep = bit1 ? c23 : c01;
        return keep + __shfl_xor(send, 32);
    };

    const int wid = blockIdx.x * 4 + w;          // 4096 waves

    for (int e = wid; e < NE; e += K1_WAVES) {
        const int s = off[e];
        const int t = off[e + 1];
        const int n = t - s;
        const int nfull = n >> 4;
        const float* vp = values + s + l15;

        float sjA[4] = {0.f, 0.f, 0.f, 0.f};
        float sjB[4] = {0.f, 0.f, 0.f, 0.f};

        int b = 0;
        // dual independent full blocks per iteration (ILP against ~2.5-wave
        // residency); full blocks need NO per-lane bounds check
        for (; b + 2 <= nfull; b += 2) {
            const _Float16 vA = (_Float16)vp[b * 16];
            const _Float16 vB = (_Float16)vp[b * 16 + 16];
            half8 A0A, A1A, A0B, A1B;
            buildA(vA, A0A, A1A);
            buildA(vB, A0B, A1B);
            chain(A0A, A1A, sjA);
            chain(A0B, A1B, sjB);
        }
        if (b < nfull) {                         // odd remaining full block
            const _Float16 vA = (_Float16)vp[b * 16];
            half8 A0A, A1A;
            buildA(vA, A0A, A1A);
            chain(A0A, A1A, sjA);
        }
        const int rem = n & 15;
        if (rem) {                               // tail block, select-masked
            const _Float16 vA =
                (_Float16)((l15 < rem) ? vp[nfull * 16] : 0.f);
            half8 A0A, A1A;
            buildA(vA, A0A, A1A);
            chainTail(A0A, A1A, sjA, rem);
        }

        float sj[4];
#pragma unroll
        for (int jf = 0; jf < 4; jf++) sj[jf] = sjA[jf] + sjB[jf];
        ev[(size_t)e * 64 + l] = reduce4(sj);    // one wave owns event e
    }
}

// ---------------- K2: rho1 + o1 + phi2 (5 fused layers), 16-EVENT TILES ----------
// r11-r12 subtraction: k2+overhead ~25us with only 313 waves across 1024 SIMDs.
// 16-event tiles -> 1250 single-wave blocks (exact, no masks), 4x parallelism.
__global__ __launch_bounds__(64) void k2_events(
    const float* __restrict__ ev,
    const float* __restrict__ W0, const float* __restrict__ B0,
    const float* __restrict__ W1, const float* __restrict__ B1,
    const float* __restrict__ W2, const float* __restrict__ B2,
    const float* __restrict__ W3, const float* __restrict__ B3,
    const float* __restrict__ W4, const float* __restrict__ B4,
    float* __restrict__ s2) {
    __shared__ __align__(16) __bf16 xt[16 * 72];   // [e][k], stride 72
    const int l   = threadIdx.x;
    const int l15 = l & 15;
    const int l4  = l >> 4;
    const int ebase = blockIdx.x * 16;             // 1250*16 = 20000 exact

    const float* Ws[5] = {W0, W1, W2, W3, W4};
    const float* Bs[5] = {B0, B1, B2, B3, B4};

    // A fragments from ev: event row e = ebase + l15
    bf16x8 A[2];
#pragma unroll
    for (int kf = 0; kf < 2; kf++) {
        const float* p = ev + (size_t)(ebase + l15) * 64 + kf * 32 + l4 * 8;
        fvec4 x = *(const fvec4*)p;
        fvec4 y = *(const fvec4*)(p + 4);
        bf16x8 a;
#pragma unroll
        for (int e2 = 0; e2 < 4; e2++) {
            a[e2]     = (__bf16)x[e2];
            a[e2 + 4] = (__bf16)y[e2];
        }
        A[kf] = a;
    }

#pragma unroll
    for (int L = 0; L < 5; L++) {
        bf16x8 Bh[2][4], Bl[2][4];
#pragma unroll
        for (int kf = 0; kf < 2; kf++)
#pragma unroll
            for (int jf = 0; jf < 4; jf++)
                load_bsplit(Ws[L] + (jf * 16 + l15) * 64 + kf * 32 + l4 * 8,
                            Bh[kf][jf], Bl[kf][jf]);

        f32x4 acc[4];
#pragma unroll
        for (int jf = 0; jf < 4; jf++) {
            const float bj = Bs[L][jf * 16 + l15];
#pragma unroll
            for (int r = 0; r < 4; r++) acc[jf][r] = bj;
        }
#pragma unroll
        for (int kf = 0; kf < 2; kf++)
#pragma unroll
            for (int jf = 0; jf < 4; jf++)
                acc[jf] = __builtin_amdgcn_mfma_f32_16x16x32_bf16(
                    A[kf], Bh[kf][jf], acc[jf], 0, 0, 0);
#pragma unroll
        for (int kf = 0; kf < 2; kf++)
#pragma unroll
            for (int jf = 0; jf < 4; jf++)
                acc[jf] = __builtin_amdgcn_mfma_f32_16x16x32_bf16(
                    A[kf], Bl[kf][jf], acc[jf], 0, 0, 0);

        if (L < 4) {
            // relu -> LDS [e][j] bf16, reload as next layer's A-frags
            // (single wave: DS ops execute in issue order, no barrier needed)
#pragma unroll
            for (int jf = 0; jf < 4; jf++) {
                const int j = jf * 16 + l15;
#pragma unroll
                for (int r = 0; r < 4; r++)
                    xt[(l4 * 4 + r) * 72 + j] =
                        (__bf16)fmaxf(acc[jf][r], 0.f);
            }
#pragma unroll
            for (int kf = 0; kf < 2; kf++)
                A[kf] = *(const bf16x8*)(xt + l15 * 72 + kf * 32 + l4 * 8);
        } else {
            // final phi2 layer: relu, sum over the 16 events, atomic into s2
            float sj[4];
#pragma unroll
            for (int jf = 0; jf < 4; jf++) {
                float s = (fmaxf(acc[jf][0], 0.f) + fmaxf(acc[jf][1], 0.f)) +
                          (fmaxf(acc[jf][2], 0.f) + fmaxf(acc[jf][3], 0.f));
                s += __shfl_xor(s, 16);
                s += __shfl_xor(s, 32);
                sj[jf] = s;
            }
            float v = (l4 == 0) ? sj[0] : (l4 == 1) ? sj[1]
                    : (l4 == 2) ? sj[2] : sj[3];
            atomicAdd(s2 + l, v);
        }
    }
}

// ---------------- K3: rho2 + output + log_softmax (tiny) ----------------
__global__ __launch_bounds__(64) void k3_final(
    const float* __restrict__ s2,
    const float* __restrict__ W0, const float* __restrict__ B0,
    const float* __restrict__ W1, const float* __restrict__ B1,
    const float* __restrict__ W2, const float* __restrict__ B2,
    float* __restrict__ out) {
    __shared__ __align__(16) float xb[64];
    __shared__ __align__(16) float yb[64];
    __shared__ float ob[10];
    const int l = threadIdx.x;

    xb[l] = s2[l];
    __syncthreads();

    float a = B0[l];
#pragma unroll
    for (int k = 0; k < 16; k++) {
        fvec4 wv = *(const fvec4*)(W0 + l * 64 + k * 4);
        fvec4 xv = *(const fvec4*)(xb + k * 4);
        a += wv[0] * xv[0] + wv[1] * xv[1] + wv[2] * xv[2] + wv[3] * xv[3];
    }
    yb[l] = fmaxf(a, 0.f);
    __syncthreads();

    float b_ = B1[l];
#pragma unroll
    for (int k = 0; k < 16; k++) {
        fvec4 wv = *(const fvec4*)(W1 + l * 64 + k * 4);
        fvec4 xv = *(const fvec4*)(yb + k * 4);
        b_ += wv[0] * xv[0] + wv[1] * xv[1] + wv[2] * xv[2] + wv[3] * xv[3];
    }
    __syncthreads();
    xb[l] = fmaxf(b_, 0.f);
    __syncthreads();

    if (l < 10) {
        float o = B2[l];
#pragma unroll
        for (int k = 0; k < 16; k++) {
            fvec4 wv = *(const fvec4*)(W2 + l * 64 + k * 4);
            fvec4 xv = *(const fvec4*)(xb + k * 4);
            o += wv[0] * xv[0] + wv[1] * xv[1] + wv[2] * xv[2] + wv[3] * xv[3];
        }
        ob[l] = o;
    }
    __syncthreads();
    if (l == 0) {
        float m = ob[0];
#pragma unroll
        for (int i = 1; i < 10; i++) m = fmaxf(m, ob[i]);
        float sum = 0.f;
#pragma unroll
        for (int i = 0; i < 10; i++) sum = sum + expf(ob[i] - m);
        float ls = logf(sum);
#pragma unroll
        for (int i = 0; i < 10; i++) out[i] = ob[i] - m - ls;
    }
}

extern "C" void kernel_launch(void* const* d_in, const int* in_sizes, int n_in,
                              void* d_out, int out_size, void* d_ws, size_t ws_size,
                              hipStream_t stream) {
    const float* values = (const float*)d_in[0];
    const int*   seg    = (const int*)d_in[1];
    const float* p1w0 = (const float*)d_in[2],  *p1b0 = (const float*)d_in[3];
    const float* p1w1 = (const float*)d_in[4],  *p1b1 = (const float*)d_in[5];
    const float* r1w0 = (const float*)d_in[6],  *r1b0 = (const float*)d_in[7];
    const float* r1w1 = (const float*)d_in[8],  *r1b1 = (const float*)d_in[9];
    const float* o1w  = (const float*)d_in[10], *o1b  = (const float*)d_in[11];
    const float* p2w0 = (const float*)d_in[12], *p2b0 = (const float*)d_in[13];
    const float* p2w1 = (const float*)d_in[14], *p2b1 = (const float*)d_in[15];
    const float* r2w0 = (const float*)d_in[16], *r2b0 = (const float*)d_in[17];
    const float* r2w1 = (const float*)d_in[18], *r2b1 = (const float*)d_in[19];
    const float* o2w  = (const float*)d_in[20], *o2b  = (const float*)d_in[21];

    float* ev  = (float*)d_ws;                      // [NE][64]
    float* s2  = ev + (size_t)NE * 64;              // [64]
    int*   off = (int*)(s2 + 64);                   // [NE+1]

    hipLaunchKernelGGL(k0_offsets, dim3((NT4 + 255) / 256), dim3(256), 0, stream,
                       seg, off, s2);
    hipLaunchKernelGGL(k1_phi1, dim3(K1_BLOCKS), dim3(256), 0, stream,
                       values, off, p1w0, p1b0, p1w1, p1b1, ev);
    hipLaunchKernelGGL(k2_events, dim3(K2_BLOCKS), dim3(64), 0, stream,
                       ev, r1w0, r1b0, r1w1, r1b1, o1w, o1b,
                       p2w0, p2b0, p2w1, p2b1, s2);
    hipLaunchKernelGGL(k3_final, dim3(1), dim3(64), 0, stream,
                       s2, r2w0, r2b0, r2w1, r2b1, o2w, o2b, (float*)d_out);
}

// Round 14
// 67.937 us; speedup vs baseline: 1.3237x; 1.3237x over previous
//
#include <hip/hip_runtime.h>

#define NT 2000000
#define NE 20000
#define NT4 (NT / 4)          // 500000, exact
#define K1_BLOCKS 1024
#define K1_WAVES (K1_BLOCKS * 4)   // 4096 -> 4.88 events/wave (balanced)
#define K2_BLOCKS ((NE + 63) / 64) // 313

using bf16x8 = __attribute__((ext_vector_type(8))) __bf16;
using half8  = __attribute__((ext_vector_type(8))) _Float16;
using half2v = __attribute__((ext_vector_type(2))) _Float16;
using f32x4  = __attribute__((ext_vector_type(4))) float;
using f32x2  = __attribute__((ext_vector_type(2))) float;
using fvec4  = __attribute__((ext_vector_type(4))) float;

// 8 consecutive f32 -> f16x8
__device__ __forceinline__ half8 load_h8(const float* __restrict__ p) {
    fvec4 a = *(const fvec4*)p;
    fvec4 b = *(const fvec4*)(p + 4);
    half8 r;
#pragma unroll
    for (int e = 0; e < 4; e++) {
        r[e]     = (_Float16)a[e];
        r[e + 4] = (_Float16)b[e];
    }
    return r;
}

// ---------------- K0: event offsets via boundary scatter + zero s2/counter -------
__global__ __launch_bounds__(256) void k0_offsets(
    const int* __restrict__ seg, int* __restrict__ off, float* __restrict__ s2,
    int* __restrict__ counter) {
    if (blockIdx.x == 0) {
        if (threadIdx.x < 64) s2[threadIdx.x] = 0.f;
        if (threadIdx.x == 64) *counter = 0;
    }
    const int g = blockIdx.x * 256 + threadIdx.x;
    if (g >= NT4) return;
    const int idx4 = g * 4;
    const int4 s = *(const int4*)(seg + idx4);
    int prev = (g == 0) ? -1 : seg[idx4 - 1];
    int vals[4] = {s.x, s.y, s.z, s.w};
#pragma unroll
    for (int k = 0; k < 4; k++) {
        const int cur = vals[k];
        if (cur != prev) {
            for (int e = prev + 1; e <= cur; ++e) off[e] = idx4 + k;
        }
        prev = cur;
    }
    if (idx4 + 3 == NT - 1) {
        for (int e = prev + 1; e <= NE; ++e) off[e] = NT;
    }
}

// ---------------- K1: fused phi1 (2 layers) + per-event sum, WAVE PER EVENT ------
// Dual independent chains per iteration (r13: 46->~35us). Occupancy pinned
// ~2.5 waves/SIMD by AGPR allocation; VALU floor ~14us (relu+fold 2/particle).
// Tripwire: FETCH_SIZE ~4.6MB (scratch spill -> revert).
__global__ __launch_bounds__(256, 4) void k1_phi1(
    const float* __restrict__ values, const int* __restrict__ off,
    const float* __restrict__ w0, const float* __restrict__ b0,
    const float* __restrict__ w1, const float* __restrict__ b1,
    float* __restrict__ ev) {
    const int tid = threadIdx.x;
    const int w   = tid >> 6;
    const int l   = tid & 63;
    const int l15 = l & 15;
    const int l4  = l >> 4;

    // B fragments for W1 (f16): lane holds col j=16jf+l15, k = 32kf+8*l4+e
    half8 Bh[2][4];
#pragma unroll
    for (int kf = 0; kf < 2; kf++)
#pragma unroll
        for (int jf = 0; jf < 4; jf++)
            Bh[kf][jf] = load_h8(w1 + (jf * 16 + l15) * 64 + kf * 32 + l4 * 8);

    // layer-1 weights as f16 pairs -> v_pk_fma_f16 in the A-build
    half2v w0h[2][4], b0h[2][4];
#pragma unroll
    for (int kf = 0; kf < 2; kf++) {
        const int kb = kf * 32 + l4 * 8;
#pragma unroll
        for (int e2 = 0; e2 < 4; e2++) {
            f32x2 wp = *(const f32x2*)(w0 + kb + 2 * e2);
            f32x2 bp = *(const f32x2*)(b0 + kb + 2 * e2);
            w0h[kf][e2] = half2v{(_Float16)wp[0], (_Float16)wp[1]};
            b0h[kf][e2] = half2v{(_Float16)bp[0], (_Float16)bp[1]};
        }
    }
    // bias as ready-made C fragment
    f32x4 biasC[4];
#pragma unroll
    for (int jf = 0; jf < 4; jf++) {
        const float bj = b1[jf * 16 + l15];
#pragma unroll
        for (int r = 0; r < 4; r++) biasC[jf][r] = bj;
    }

    // h1 = relu(v*w0+b0) in packed f16, directly in A-fragment layout
    auto buildA = [&](_Float16 v, half8& A0, half8& A1) {
        const half2v vv = {v, v};
#pragma unroll
        for (int e2 = 0; e2 < 4; e2++) {
            half2v h0 = vv * w0h[0][e2] + b0h[0][e2];   // v_pk_fma_f16
            half2v h1 = vv * w0h[1][e2] + b0h[1][e2];
            const _Float16 z = (_Float16)0.f;
            A0[2 * e2]     = h0[0] > z ? h0[0] : z;
            A0[2 * e2 + 1] = h0[1] > z ? h0[1] : z;
            A1[2 * e2]     = h1[0] > z ? h1[0] : z;
            A1[2 * e2 + 1] = h1[1] > z ? h1[1] : z;
        }
    };
    // 2-MFMA chain per jf, relu'd and folded into running partials
    auto chain = [&](const half8& A0, const half8& A1, float* sj) {
#pragma unroll
        for (int jf = 0; jf < 4; jf++) {
            f32x4 tt = __builtin_amdgcn_mfma_f32_16x16x32_f16(
                A0, Bh[0][jf], biasC[jf], 0, 0, 0);
            tt = __builtin_amdgcn_mfma_f32_16x16x32_f16(
                A1, Bh[1][jf], tt, 0, 0, 0);
            sj[jf] += (fmaxf(tt[0], 0.f) + fmaxf(tt[1], 0.f)) +
                      (fmaxf(tt[2], 0.f) + fmaxf(tt[3], 0.f));
        }
    };
    auto chainTail = [&](const half8& A0, const half8& A1, float* sj, int rem) {
#pragma unroll
        for (int jf = 0; jf < 4; jf++) {
            f32x4 tt = __builtin_amdgcn_mfma_f32_16x16x32_f16(
                A0, Bh[0][jf], biasC[jf], 0, 0, 0);
            tt = __builtin_amdgcn_mfma_f32_16x16x32_f16(
                A1, Bh[1][jf], tt, 0, 0, 0);
            float s = 0.f;
#pragma unroll
            for (int r = 0; r < 4; r++) {
                const bool ok = (l4 * 4 + r) < rem;
                s += ok ? fmaxf(tt[r], 0.f) : 0.f;
            }
            sj[jf] += s;
        }
    };

    // 2-step butterfly: lane l ends holding full column sum of feature j==l
    const bool bit0 = (l & 16) != 0;
    const bool bit1 = (l & 32) != 0;
    auto reduce4 = [&](const float sj[4]) -> float {
        float send01 = bit0 ? sj[0] : sj[1];
        float keep01 = bit0 ? sj[1] : sj[0];
        float c01 = keep01 + __shfl_xor(send01, 16);
        float send23 = bit0 ? sj[2] : sj[3];
        float keep23 = bit0 ? sj[3] : sj[2];
        float c23 = keep23 + __shfl_xor(send23, 16);
        float send = bit1 ? c01 : c23;
        float keep = bit1 ? c23 : c01;
        return keep + __shfl_xor(send, 32);
    };

    const int wid = blockIdx.x * 4 + w;          // 4096 waves

    for (int e = wid; e < NE; e += K1_WAVES) {
        const int s = off[e];
        const int t = off[e + 1];
        const int n = t - s;
        const int nfull = n >> 4;
        const float* vp = values + s + l15;

        float sjA[4] = {0.f, 0.f, 0.f, 0.f};
        float sjB[4] = {0.f, 0.f, 0.f, 0.f};

        int b = 0;
        for (; b + 2 <= nfull; b += 2) {
            const _Float16 vA = (_Float16)vp[b * 16];
            const _Float16 vB = (_Float16)vp[b * 16 + 16];
            half8 A0A, A1A, A0B, A1B;
            buildA(vA, A0A, A1A);
            buildA(vB, A0B, A1B);
            chain(A0A, A1A, sjA);
            chain(A0B, A1B, sjB);
        }
        if (b < nfull) {
            const _Float16 vA = (_Float16)vp[b * 16];
            half8 A0A, A1A;
            buildA(vA, A0A, A1A);
            chain(A0A, A1A, sjA);
        }
        const int rem = n & 15;
        if (rem) {
            const _Float16 vA =
                (_Float16)((l15 < rem) ? vp[nfull * 16] : 0.f);
            half8 A0A, A1A;
            buildA(vA, A0A, A1A);
            chainTail(A0A, A1A, sjA, rem);
        }

        float sj[4];
#pragma unroll
        for (int jf = 0; jf < 4; jf++) sj[jf] = sjA[jf] + sjB[jf];
        ev[(size_t)e * 64 + l] = reduce4(sj);    // one wave owns event e
    }
}

// ------- K2: rho1+o1+phi2 (5 fused layers, f16 single) + event-sum + k3 tail -----
// r13 lesson: 16-event tiles = 3x regression (weight reload per tiny block).
// Back to 64-event/wave, 313 blocks; f16 single weights halve MFMA count vs
// bf16 hi/lo. Last-finishing block runs rho2+out+log_softmax (saves a launch).
__global__ __launch_bounds__(64) void k2_events(
    const float* __restrict__ ev,
    const float* __restrict__ W0, const float* __restrict__ B0,
    const float* __restrict__ W1, const float* __restrict__ B1,
    const float* __restrict__ W2, const float* __restrict__ B2,
    const float* __restrict__ W3, const float* __restrict__ B3,
    const float* __restrict__ W4, const float* __restrict__ B4,
    float* __restrict__ s2, int* __restrict__ counter,
    const float* __restrict__ R0, const float* __restrict__ Rb0,
    const float* __restrict__ R1, const float* __restrict__ Rb1,
    const float* __restrict__ OW, const float* __restrict__ OB,
    float* __restrict__ out) {
    __shared__ __align__(16) _Float16 xt[64 * 72];   // [e][k], stride 72
    const int l   = threadIdx.x;
    const int l15 = l & 15;
    const int l4  = l >> 4;
    const int ebase = blockIdx.x * 64;

    const float* Ws[5] = {W0, W1, W2, W3, W4};
    const float* Bs[5] = {B0, B1, B2, B3, B4};

    // A fragments from ev (f32 -> f16), masked for e >= NE
    half8 A[4][2];
#pragma unroll
    for (int pf = 0; pf < 4; pf++) {
        const int e = ebase + pf * 16 + l15;
#pragma unroll
        for (int kf = 0; kf < 2; kf++) {
            half8 a;
            if (e < NE) {
                a = load_h8(ev + (size_t)e * 64 + kf * 32 + l4 * 8);
            } else {
#pragma unroll
                for (int e2 = 0; e2 < 8; e2++) a[e2] = (_Float16)0.f;
            }
            A[pf][kf] = a;
        }
    }

#pragma unroll
    for (int L = 0; L < 5; L++) {
        half8 Bh[2][4];
#pragma unroll
        for (int kf = 0; kf < 2; kf++)
#pragma unroll
            for (int jf = 0; jf < 4; jf++)
                Bh[kf][jf] = load_h8(Ws[L] + (jf * 16 + l15) * 64 +
                                     kf * 32 + l4 * 8);

        f32x4 acc[4][4];
#pragma unroll
        for (int jf = 0; jf < 4; jf++) {
            const float bj = Bs[L][jf * 16 + l15];
#pragma unroll
            for (int pf = 0; pf < 4; pf++)
#pragma unroll
                for (int r = 0; r < 4; r++) acc[pf][jf][r] = bj;
        }
#pragma unroll
        for (int kf = 0; kf < 2; kf++)
#pragma unroll
            for (int pf = 0; pf < 4; pf++)
#pragma unroll
                for (int jf = 0; jf < 4; jf++)
                    acc[pf][jf] = __builtin_amdgcn_mfma_f32_16x16x32_f16(
                        A[pf][kf], Bh[kf][jf], acc[pf][jf], 0, 0, 0);

        if (L < 4) {
            // relu -> LDS [e][j] f16, reload as next layer's A-frags
#pragma unroll
            for (int pf = 0; pf < 4; pf++)
#pragma unroll
                for (int jf = 0; jf < 4; jf++) {
                    const int j = jf * 16 + l15;
#pragma unroll
                    for (int r = 0; r < 4; r++)
                        xt[(pf * 16 + l4 * 4 + r) * 72 + j] =
                            (_Float16)fmaxf(acc[pf][jf][r], 0.f);
                }
#pragma unroll
            for (int pf = 0; pf < 4; pf++)
#pragma unroll
                for (int kf = 0; kf < 2; kf++)
                    A[pf][kf] = *(const half8*)(xt + (pf * 16 + l15) * 72 +
                                                kf * 32 + l4 * 8);
        } else {
            // final phi2 layer: relu, masked sum over events, atomic into s2
            float sj[4];
#pragma unroll
            for (int jf = 0; jf < 4; jf++) {
                float s = 0.f;
#pragma unroll
                for (int pf = 0; pf < 4; pf++)
#pragma unroll
                    for (int r = 0; r < 4; r++) {
                        const int e = ebase + pf * 16 + l4 * 4 + r;
                        float v = fmaxf(acc[pf][jf][r], 0.f);
                        s += (e < NE) ? v : 0.f;
                    }
                s += __shfl_xor(s, 16);
                s += __shfl_xor(s, 32);
                sj[jf] = s;
            }
            float v = (l4 == 0) ? sj[0] : (l4 == 1) ? sj[1]
                    : (l4 == 2) ? sj[2] : sj[3];
            atomicAdd(s2 + l, v);
        }
    }

    // ---- fused rho2 + output + log_softmax: last block to finish does it ----
    __shared__ int is_last;
    __threadfence();
    if (l == 0) {
        const int c = atomicAdd(counter, 1);
        is_last = (c == (int)gridDim.x - 1);
    }
    __syncthreads();
    if (!is_last) return;

    __shared__ __align__(16) float xb[64];
    __shared__ __align__(16) float yb[64];
    __shared__ float ob[10];

    xb[l] = atomicAdd(s2 + l, 0.f);   // coherent read (fence+counter ordered)
    __syncthreads();

    float a0 = Rb0[l];
#pragma unroll
    for (int k = 0; k < 16; k++) {
        fvec4 wv = *(const fvec4*)(R0 + l * 64 + k * 4);
        fvec4 xv = *(const fvec4*)(xb + k * 4);
        a0 += wv[0] * xv[0] + wv[1] * xv[1] + wv[2] * xv[2] + wv[3] * xv[3];
    }
    yb[l] = fmaxf(a0, 0.f);
    __syncthreads();

    float b_ = Rb1[l];
#pragma unroll
    for (int k = 0; k < 16; k++) {
        fvec4 wv = *(const fvec4*)(R1 + l * 64 + k * 4);
        fvec4 xv = *(const fvec4*)(yb + k * 4);
        b_ += wv[0] * xv[0] + wv[1] * xv[1] + wv[2] * xv[2] + wv[3] * xv[3];
    }
    __syncthreads();
    xb[l] = fmaxf(b_, 0.f);
    __syncthreads();

    if (l < 10) {
        float o = OB[l];
#pragma unroll
        for (int k = 0; k < 16; k++) {
            fvec4 wv = *(const fvec4*)(OW + l * 64 + k * 4);
            fvec4 xv = *(const fvec4*)(xb + k * 4);
            o += wv[0] * xv[0] + wv[1] * xv[1] + wv[2] * xv[2] + wv[3] * xv[3];
        }
        ob[l] = o;
    }
    __syncthreads();
    if (l == 0) {
        float m = ob[0];
#pragma unroll
        for (int i = 1; i < 10; i++) m = fmaxf(m, ob[i]);
        float sum = 0.f;
#pragma unroll
        for (int i = 0; i < 10; i++) sum = sum + expf(ob[i] - m);
        float ls = logf(sum);
#pragma unroll
        for (int i = 0; i < 10; i++) out[i] = ob[i] - m - ls;
    }
}

extern "C" void kernel_launch(void* const* d_in, const int* in_sizes, int n_in,
                              void* d_out, int out_size, void* d_ws, size_t ws_size,
                              hipStream_t stream) {
    const float* values = (const float*)d_in[0];
    const int*   seg    = (const int*)d_in[1];
    const float* p1w0 = (const float*)d_in[2],  *p1b0 = (const float*)d_in[3];
    const float* p1w1 = (const float*)d_in[4],  *p1b1 = (const float*)d_in[5];
    const float* r1w0 = (const float*)d_in[6],  *r1b0 = (const float*)d_in[7];
    const float* r1w1 = (const float*)d_in[8],  *r1b1 = (const float*)d_in[9];
    const float* o1w  = (const float*)d_in[10], *o1b  = (const float*)d_in[11];
    const float* p2w0 = (const float*)d_in[12], *p2b0 = (const float*)d_in[13];
    const float* p2w1 = (const float*)d_in[14], *p2b1 = (const float*)d_in[15];
    const float* r2w0 = (const float*)d_in[16], *r2b0 = (const float*)d_in[17];
    const float* r2w1 = (const float*)d_in[18], *r2b1 = (const float*)d_in[19];
    const float* o2w  = (const float*)d_in[20], *o2b  = (const float*)d_in[21];

    float* ev  = (float*)d_ws;                      // [NE][64]
    float* s2  = ev + (size_t)NE * 64;              // [64]
    int*   off = (int*)(s2 + 64);                   // [NE+1]
    int*   counter = off + (NE + 1);                // [1]

    hipLaunchKernelGGL(k0_offsets, dim3((NT4 + 255) / 256), dim3(256), 0, stream,
                       seg, off, s2, counter);
    hipLaunchKernelGGL(k1_phi1, dim3(K1_BLOCKS), dim3(256), 0, stream,
                       values, off, p1w0, p1b0, p1w1, p1b1, ev);
    hipLaunchKernelGGL(k2_events, dim3(K2_BLOCKS), dim3(64), 0, stream,
                       ev, r1w0, r1b0, r1w1, r1b1, o1w, o1b,
                       p2w0, p2b0, p2w1, p2b1, s2, counter,
                       r2w0, r2b0, r2w1, r2b1, o2w, o2b, (float*)d_out);
}